// Round 15
// baseline (99.429 us; speedup 1.0000x reference)
//
#include <hip/hip_runtime.h>
#include <math.h>

#define B 64
#define N 256
#define C 512

typedef float nfloat4 __attribute__((ext_vector_type(4)));

// guide modality for module m = 3*mi + j
__device__ __forceinline__ int guide_of(int m) {
    int mi = m / 3, j = m % 3;
    return (j == 0) ? mi : (j == 1 ? ((mi == 0) ? 1 : 0) : ((mi == 2) ? 1 : 2));
}

template<int NW>
__device__ __forceinline__ float breduce_sum(float v, volatile float* red, int t) {
    int w = t >> 6, l = t & 63;
#pragma unroll
    for (int mm = 1; mm < 64; mm <<= 1) v += __shfl_xor(v, mm);
    __syncthreads();
    if (l == 0) red[w] = v;
    __syncthreads();
    float s = red[0];
#pragma unroll
    for (int i = 1; i < NW; i++) s += red[i];
    return s;
}

__device__ __forceinline__ float dot4(float4 a, float4 b) {
    return a.x * b.x + a.y * b.y + a.z * b.z + a.w * b.w;
}

// L3-warm one 256KB patch chunk (64 float4/thread), sink the sum to scrap.
__device__ __forceinline__ void warm_chunk(int chunk, int t,
                                           const float* p0, const float* p1, const float* p2,
                                           float* scrap) {
    int mi = chunk >> 7;                       // 128 chunks of 65536 floats per modality
    const float* p = (mi == 0) ? p0 : (mi == 1 ? p1 : p2);
    const float4* base = (const float4*)(p + (size_t)(chunk & 127) * 65536);
    float4 s = make_float4(0.f, 0.f, 0.f, 0.f);
#pragma unroll 8
    for (int i = 0; i < 64; i++) {
        float4 v = base[t + 256 * i];
        s.x += v.x; s.y += v.y; s.z += v.z; s.w += v.w;
    }
    float r = s.x + s.y + s.z + s.w;
#pragma unroll
    for (int mm = 1; mm < 64; mm <<= 1) r += __shfl_xor(r, mm);
    if (t == 0) scrap[chunk] = r;
}

// Fused: qproj partials (0..575) + mlp fc1 tiles (576..719) + gn (720..722)
// + patch L3-warm (723..1022, chunks 0..299)
__global__ __launch_bounds__(256) void k_proj_mlp(const float* g0, const float* g1, const float* g2,
                                                  const float* qw, const float* w1,
                                                  const float* p0, const float* p1, const float* p2,
                                                  float* part, float* h1part, float* gn,
                                                  float* scrap) {
    int bid = blockIdx.x;
    int t = threadIdx.x;
    __shared__ float gt[64 * 132];  // padded stride 132: bank (4b+e)%32, conflict-free
    if (bid < 576) {
        int cx = bid & 7, m = (bid >> 3) % 9, ks = bid / 72;
        int e0 = ks * 64;
        int gi = guide_of(m);
        const float* g = (gi == 0) ? g0 : (gi == 1 ? g1 : g2);
        for (int idx = t; idx < 1024; idx += 256) {
            int r = idx >> 4, c4 = idx & 15;
            ((float4*)&gt[r * 132])[c4] = ((const float4*)(g + (size_t)r * C + e0))[c4];
        }
        __syncthreads();
        int c0 = cx * 64 + 4 * (t & 15);
        int b0 = 4 * (t >> 4);
        float4 acc[4];
#pragma unroll
        for (int j = 0; j < 4; j++) acc[j] = make_float4(0.f, 0.f, 0.f, 0.f);
        const float* W = qw + (size_t)m * C * C + (size_t)e0 * C + c0;
#pragma unroll 4
        for (int e = 0; e < 64; e++) {
            float4 wv = *(const float4*)(W + (size_t)e * C);
#pragma unroll
            for (int j = 0; j < 4; j++) {
                float gv = gt[(b0 + j) * 132 + e];
                acc[j].x += gv * wv.x; acc[j].y += gv * wv.y;
                acc[j].z += gv * wv.z; acc[j].w += gv * wv.w;
            }
        }
#pragma unroll
        for (int j = 0; j < 4; j++)
            *(float4*)(part + (size_t)ks * 294912 + ((size_t)m * B + b0 + j) * C + c0) = acc[j];
    } else if (bid < 720) {
        int r = bid - 576;  // 0..143 : (cx=4, mi=3, ks=12)
        int cx = r & 3, mi = (r >> 2) % 3, ks = r / 12;
        int e0 = ks * 128;
        const float* g = (e0 < 512) ? g0 : (e0 < 1024 ? g1 : g2);
        int eo = e0 & 511;
        for (int idx = t; idx < 2048; idx += 256) {
            int rr = idx >> 5, c4 = idx & 31;
            ((float4*)&gt[rr * 132])[c4] = ((const float4*)(g + (size_t)rr * C + eo))[c4];
        }
        __syncthreads();
        int c0 = cx * 64 + 4 * (t & 15);
        int b0 = 4 * (t >> 4);
        float4 acc[4];
#pragma unroll
        for (int j = 0; j < 4; j++) acc[j] = make_float4(0.f, 0.f, 0.f, 0.f);
        const float* W = w1 + ((size_t)mi * 1536 + e0) * 256 + c0;
#pragma unroll 4
        for (int e = 0; e < 128; e++) {
            float4 wv = *(const float4*)(W + (size_t)e * 256);
#pragma unroll
            for (int j = 0; j < 4; j++) {
                float gv = gt[(b0 + j) * 132 + e];
                acc[j].x += gv * wv.x; acc[j].y += gv * wv.y;
                acc[j].z += gv * wv.z; acc[j].w += gv * wv.w;
            }
        }
#pragma unroll
        for (int j = 0; j < 4; j++)
            *(float4*)(h1part + (((size_t)ks * 3 + mi) * B + b0 + j) * 256 + c0) = acc[j];
    } else if (bid < 723) {
        int gm = bid - 720;  // 0..2
        const float* g = (gm == 0) ? g0 : (gm == 1 ? g1 : g2);
        int wv = t >> 6, l = t & 63;
        for (int r = wv; r < 64; r += 4) {
            const float4* gv = (const float4*)(g + (size_t)r * C);
            float4 a = gv[l], b2 = gv[64 + l];
            float n2 = dot4(a, a) + dot4(b2, b2);
#pragma unroll
            for (int mm = 1; mm < 64; mm <<= 1) n2 += __shfl_xor(n2, mm);
            float inv = 1.0f / fmaxf(sqrtf(n2), 1e-8f);
            float4* o = (float4*)(gn + ((size_t)gm * B + r) * C);
            a.x *= inv; a.y *= inv; a.z *= inv; a.w *= inv;
            b2.x *= inv; b2.y *= inv; b2.z *= inv; b2.w *= inv;
            o[l] = a; o[64 + l] = b2;
        }
    } else {
        warm_chunk(bid - 723, t, p0, p1, p2, scrap);  // chunks 0..299
    }
}

// kpart[ds][m][b][c] = sum_{d in slice ds} kw[m,c,d]*q[m,b,d] (cx<8, 4x4 tiling)
// cx>=8 spare blocks: widx<192 -> adaptive-weight MLP once per (mi,b) -> wmix;
// widx in [192,276) -> patch L3-warm chunks 300..383.
__global__ __launch_bounds__(256) void k_kproj(const float* kw, const float* part,
                                               const float* qb, const float* kb,
                                               const float* h1part,
                                               const float* b1, const float* lng, const float* lnb,
                                               const float* w2, const float* b2,
                                               const float* w3, const float* b3,
                                               const float* p0, const float* p1, const float* p2,
                                               float* kpart, float* qkb_part, float* wmix,
                                               float* scrap) {
    int cx = blockIdx.x, m = blockIdx.y, ds = blockIdx.z;
    int t = threadIdx.x;
    if (cx >= 8) {
        int widx = (cx - 8) * 72 + m * 8 + ds;  // 0..359
        if (widx >= 192) {
            if (widx < 276) warm_chunk(300 + widx - 192, t, p0, p1, p2, scrap);
            return;
        }
        int mi = widx >> 6;    // 0..2
        int b = widx & 63;
        __shared__ float h1[256];
        __shared__ float h2p[4][64];
        __shared__ float h2[64];
        __shared__ float redm[4];
        float a1 = b1[mi * 256 + t];
#pragma unroll
        for (int ks = 0; ks < 12; ks++) a1 += h1part[(((size_t)ks * 3 + mi) * B + b) * 256 + t];
        float total = breduce_sum<4>(a1, redm, t);
        float mean = total * (1.0f / 256.0f);
        float dv = a1 - mean;
        float vtot = breduce_sum<4>(dv * dv, redm, t);
        float var = vtot * (1.0f / 256.0f);
        float x = dv / sqrtf(var + 1e-5f) * lng[mi * 256 + t] + lnb[mi * 256 + t];
        x = 0.5f * x * (1.0f + erff(x * 0.70710678118654752f));
        h1[t] = x;
        __syncthreads();
        {
            int col = t & 63, sl = t >> 6;
            float a2 = 0.f;
            const float* W2 = w2 + (size_t)mi * 256 * 64 + col;
#pragma unroll 8
            for (int e = sl * 64; e < sl * 64 + 64; e++) a2 += h1[e] * W2[(size_t)e * 64];
            h2p[sl][col] = a2;
        }
        __syncthreads();
        if (t < 64) {
            float a2 = b2[mi * 64 + t];
#pragma unroll
            for (int s2 = 0; s2 < 4; s2++) a2 += h2p[s2][t];
            a2 = 0.5f * a2 * (1.0f + erff(a2 * 0.70710678118654752f));
            h2[t] = a2;
        }
        __syncthreads();
        if (t == 0) {
            float l3[3];
            for (int j = 0; j < 3; j++) {
                float a3 = b3[mi * 3 + j];
                for (int e = 0; e < 64; e++) a3 += h2[e] * w3[((size_t)mi * 64 + e) * 3 + j];
                l3[j] = a3;
            }
            float mx = fmaxf(l3[0], fmaxf(l3[1], l3[2]));
            float e0 = expf(l3[0] - mx), e1 = expf(l3[1] - mx), e2 = expf(l3[2] - mx);
            float inv = 1.0f / (e0 + e1 + e2);
            wmix[((size_t)mi * B + b) * 4 + 0] = e0 * inv;
            wmix[((size_t)mi * B + b) * 4 + 1] = e1 * inv;
            wmix[((size_t)mi * B + b) * 4 + 2] = e2 * inv;
        }
        return;
    }
    int c0b = cx * 64, d0 = ds * 64;
    __shared__ float kt[64][65];  // [c][d] padded: bank (c+d)%32
    __shared__ float qt[64][65];  // [b][d] padded
    for (int idx = t; idx < 1024; idx += 256) {
        int r = idx >> 4, c4 = idx & 15;
        float4 kv4 = *(const float4*)(kw + ((size_t)m * C + c0b + r) * C + d0 + c4 * 4);
        kt[r][c4 * 4 + 0] = kv4.x; kt[r][c4 * 4 + 1] = kv4.y;
        kt[r][c4 * 4 + 2] = kv4.z; kt[r][c4 * 4 + 3] = kv4.w;
        float4 s = *(const float4*)(qb + (size_t)m * C + d0 + c4 * 4);
        const float* pp = part + ((size_t)m * B + r) * C + d0 + c4 * 4;
#pragma unroll
        for (int ks = 0; ks < 8; ks++) {
            float4 v = *(const float4*)(pp + (size_t)ks * 294912);
            s.x += v.x; s.y += v.y; s.z += v.z; s.w += v.w;
        }
        qt[r][c4 * 4 + 0] = s.x; qt[r][c4 * 4 + 1] = s.y;
        qt[r][c4 * 4 + 2] = s.z; qt[r][c4 * 4 + 3] = s.w;
    }
    __syncthreads();
    int c0 = 4 * (t & 15);
    int b0 = 4 * (t >> 4);
    float4 acc[4];
#pragma unroll
    for (int j = 0; j < 4; j++) acc[j] = make_float4(0.f, 0.f, 0.f, 0.f);
#pragma unroll 4
    for (int d = 0; d < 64; d++) {
        float k0 = kt[c0 + 0][d], k1 = kt[c0 + 1][d], k2 = kt[c0 + 2][d], k3 = kt[c0 + 3][d];
#pragma unroll
        for (int j = 0; j < 4; j++) {
            float qv = qt[b0 + j][d];
            acc[j].x += qv * k0; acc[j].y += qv * k1;
            acc[j].z += qv * k2; acc[j].w += qv * k3;
        }
    }
#pragma unroll
    for (int j = 0; j < 4; j++)
        *(float4*)(kpart + (size_t)ds * 294912 + ((size_t)m * B + b0 + j) * C + c0b + c0) = acc[j];
    if (cx == 0 && t < 64) {
        float s = 0.f;
        const float* kbp = kb + (size_t)m * C + d0;
        for (int d = 0; d < 64; d++) s += qt[t][d] * kbp[d];
        qkb_part[((size_t)m * 8 + ds) * B + t] = s;
    }
}

// logits: grid (B, 3, 8) x 256; 32 tokens/block; 8 lanes/token; gn precomputed.
__global__ __launch_bounds__(256) void k_logits(const float* p0, const float* p1, const float* p2,
                                                const float* kpart, const float* qkb_part,
                                                const float* gn, float* lgt) {
    int b = blockIdx.x, mi = blockIdx.y, ns = blockIdx.z;
    int t = threadIdx.x, w = t >> 6, l = t & 63;
    const float* p = (mi == 0) ? p0 : (mi == 1 ? p1 : p2);
    int s = l & 7, tl = l >> 3;
    int n = ns * 32 + w * 8 + tl;
    const float4* pbase = (const float4*)(p + (size_t)b * N * C);
    const float4* prow = pbase + (size_t)n * 128;
    float4 pf[8];
#pragma unroll
    for (int i = 0; i < 8; i++) pf[i] = prow[s + 8 * i];
    __shared__ float q6[6][512];
    __shared__ float qkb_s[3];
    for (int idx = t; idx < 768; idx += 256) {
        int row = idx >> 7, c4 = idx & 127;
        float4 v;
        if (row < 3) {
            int m = 3 * mi + row;
            const float4* kp = (const float4*)kpart + ((size_t)m * B + b) * 128 + c4;
            v = kp[0];
#pragma unroll
            for (int ds = 1; ds < 8; ds++) {
                float4 u = kp[(size_t)ds * 73728];
                v.x += u.x; v.y += u.y; v.z += u.z; v.w += u.w;
            }
        } else {
            int gi = guide_of(3 * mi + row - 3);
            v = ((const float4*)(gn + ((size_t)gi * B + b) * C))[c4];
        }
        ((float4*)q6[row])[c4] = v;
    }
    if (t < 3) {
        int m = 3 * mi + t;
        float sq = 0.f;
#pragma unroll
        for (int ds = 0; ds < 8; ds++) sq += qkb_part[((size_t)m * 8 + ds) * B + b];
        qkb_s[t] = sq;
    }
    __syncthreads();
    const float SCALE = 0.044194173824159216f;  // 512^-0.5
    float* L = lgt + (size_t)(mi * B + b) * 3 * N;
    const float4* Q0 = (const float4*)q6[0];
    const float4* Q1 = (const float4*)q6[1];
    const float4* Q2 = (const float4*)q6[2];
    const float4* G0 = (const float4*)q6[3];
    const float4* G1 = (const float4*)q6[4];
    const float4* G2 = (const float4*)q6[5];
    {
        float pp = 0.f, dj0 = 0.f, dj1 = 0.f, dj2 = 0.f, cj0 = 0.f, cj1 = 0.f, cj2 = 0.f;
#pragma unroll
        for (int i = 0; i < 16; i++) {
            int o = s + 8 * i;
            float4 pv = (i < 8) ? pf[i] : prow[o];
            pp  += dot4(pv, pv);
            dj0 += dot4(pv, Q0[o]);
            dj1 += dot4(pv, Q1[o]);
            dj2 += dot4(pv, Q2[o]);
            cj0 += dot4(pv, G0[o]);
            cj1 += dot4(pv, G1[o]);
            cj2 += dot4(pv, G2[o]);
        }
#pragma unroll
        for (int mm = 1; mm < 8; mm <<= 1) {
            pp  += __shfl_xor(pp, mm);
            dj0 += __shfl_xor(dj0, mm);
            dj1 += __shfl_xor(dj1, mm);
            dj2 += __shfl_xor(dj2, mm);
            cj0 += __shfl_xor(cj0, mm);
            cj1 += __shfl_xor(cj1, mm);
            cj2 += __shfl_xor(cj2, mm);
        }
        if (s == 0) {
            float rn = fmaxf(sqrtf(pp), 1e-8f);
            float ic = 1.0f / (rn * 0.3f);
            L[0 * N + n] = (dj0 + qkb_s[0]) * SCALE + cj0 * ic;
            L[1 * N + n] = (dj1 + qkb_s[1]) * SCALE + cj1 * ic;
            L[2 * N + n] = (dj2 + qkb_s[2]) * SCALE + cj2 * ic;
        }
    }
}

// finscale: grid (B, 3, 8) x 256, forward order. Score-only prologue (MLP in
// kproj -> wmix); logit loads then 8-float4 slab prefetch (cached loads drain
// under the score phase via in-order vmcnt); batched 3-wide reductions.
__global__ __launch_bounds__(256) void k_finscale(const float* lgt, const float* wmix,
                                                  const float* p0, const float* p1, const float* p2,
                                                  float* out) {
    int b = blockIdx.x, mi = blockIdx.y, ns = blockIdx.z, t = threadIdx.x;
    int w = t >> 6, l = t & 63;
    const float* L = lgt + (size_t)(mi * B + b) * 3 * N;
    float wj0 = wmix[((size_t)mi * B + b) * 4 + 0];
    float wj1 = wmix[((size_t)mi * B + b) * 4 + 1];
    float wj2 = wmix[((size_t)mi * B + b) * 4 + 2];
    float v0 = L[0 * N + t], v1 = L[1 * N + t], v2 = L[2 * N + t];
    const float* p = (mi == 0) ? p0 : (mi == 1 ? p1 : p2);
    const float4* pslab = (const float4*)(p + (size_t)b * N * C + (size_t)ns * 32 * C);
    float4 pref[8];
#pragma unroll
    for (int i = 0; i < 8; i++) pref[i] = pslab[t + 256 * i];
    __shared__ float red3[3][4];
    __shared__ float sc[256];
    __shared__ float mks[256];
    __shared__ float thr_s;
    // round 1: batched max
    float m0 = v0, m1 = v1, m2 = v2;
#pragma unroll
    for (int mm = 1; mm < 64; mm <<= 1) {
        m0 = fmaxf(m0, __shfl_xor(m0, mm));
        m1 = fmaxf(m1, __shfl_xor(m1, mm));
        m2 = fmaxf(m2, __shfl_xor(m2, mm));
    }
    __syncthreads();
    if (l == 0) { red3[0][w] = m0; red3[1][w] = m1; red3[2][w] = m2; }
    __syncthreads();
    float mx0 = red3[0][0], mx1 = red3[1][0], mx2 = red3[2][0];
#pragma unroll
    for (int i = 1; i < 4; i++) {
        mx0 = fmaxf(mx0, red3[0][i]); mx1 = fmaxf(mx1, red3[1][i]); mx2 = fmaxf(mx2, red3[2][i]);
    }
    float e0 = expf(v0 - mx0), e1 = expf(v1 - mx1), e2 = expf(v2 - mx2);
    // round 2: batched sum of e
    float s0 = e0, s1 = e1, s2 = e2;
#pragma unroll
    for (int mm = 1; mm < 64; mm <<= 1) {
        s0 += __shfl_xor(s0, mm); s1 += __shfl_xor(s1, mm); s2 += __shfl_xor(s2, mm);
    }
    __syncthreads();
    if (l == 0) { red3[0][w] = s0; red3[1][w] = s1; red3[2][w] = s2; }
    __syncthreads();
    float t0 = red3[0][0], t1 = red3[1][0], t2 = red3[2][0];
#pragma unroll
    for (int i = 1; i < 4; i++) { t0 += red3[0][i]; t1 += red3[1][i]; t2 += red3[2][i]; }
    float pr0 = e0 / t0, pr1 = e1 / t1, pr2 = e2 / t2;
    // round 3: batched sum of pr
    float u0 = pr0, u1 = pr1, u2 = pr2;
#pragma unroll
    for (int mm = 1; mm < 64; mm <<= 1) {
        u0 += __shfl_xor(u0, mm); u1 += __shfl_xor(u1, mm); u2 += __shfl_xor(u2, mm);
    }
    __syncthreads();
    if (l == 0) { red3[0][w] = u0; red3[1][w] = u1; red3[2][w] = u2; }
    __syncthreads();
    float tt0 = red3[0][0], tt1 = red3[1][0], tt2 = red3[2][0];
#pragma unroll
    for (int i = 1; i < 4; i++) { tt0 += red3[0][i]; tt1 += red3[1][i]; tt2 += red3[2][i]; }
    float dv0 = pr0 - tt0 * (1.0f / 256.0f);
    float dv1 = pr1 - tt1 * (1.0f / 256.0f);
    float dv2 = pr2 - tt2 * (1.0f / 256.0f);
    // round 4: batched sum of dv*dv
    float q0 = dv0 * dv0, q1 = dv1 * dv1, q2 = dv2 * dv2;
#pragma unroll
    for (int mm = 1; mm < 64; mm <<= 1) {
        q0 += __shfl_xor(q0, mm); q1 += __shfl_xor(q1, mm); q2 += __shfl_xor(q2, mm);
    }
    __syncthreads();
    if (l == 0) { red3[0][w] = q0; red3[1][w] = q1; red3[2][w] = q2; }
    __syncthreads();
    float vt0 = red3[0][0], vt1 = red3[1][0], vt2 = red3[2][0];
#pragma unroll
    for (int i = 1; i < 4; i++) { vt0 += red3[0][i]; vt1 += red3[1][i]; vt2 += red3[2][i]; }
    float sd0 = sqrtf(vt0 * (1.0f / 255.0f)) + 1e-5f;
    float sd1 = sqrtf(vt1 * (1.0f / 255.0f)) + 1e-5f;
    float sd2 = sqrtf(vt2 * (1.0f / 255.0f)) + 1e-5f;
    float sg0 = 1.0f / (1.0f + expf(-(dv0 / sd0)));
    float sg1 = 1.0f / (1.0f + expf(-(dv1 / sd1)));
    float sg2 = 1.0f / (1.0f + expf(-(dv2 / sd2)));
    float score = wj0 * sg0;
    score += wj1 * sg1;
    score += wj2 * sg2;
    sc[t] = score;
    __syncthreads();
    {
        int cl = 0, ce = 0;
        for (int m2i = 0; m2i < N; m2i++) {
            float v2i = sc[m2i];
            cl += (v2i < score) ? 1 : 0;
            ce += (v2i == score) ? 1 : 0;
        }
        if (cl <= 102 && 102 < cl + ce) thr_s = score;
    }
    __syncthreads();
    float thr = thr_s;
    float mk = 1.0f / (1.0f + expf(-(score - thr) * (1.0f / 0.3f)));
    mks[t] = mk;
    if ((t >> 5) == ns)
        out[(size_t)3 * B * N * C + ((size_t)mi * B + b) * N + t] = mk;
    __syncthreads();
    // --- store phase: prefetched 8, then stream the last 8 ---
    nfloat4* oslab = (nfloat4*)(out + (size_t)mi * B * N * C + (size_t)b * N * C
                                + (size_t)ns * 32 * C);
#pragma unroll
    for (int i = 0; i < 8; i++) {
        int idx = t + 256 * i;
        float mkv = mks[ns * 32 + (idx >> 7)];
        nfloat4 nv;
        nv.x = pref[i].x * mkv; nv.y = pref[i].y * mkv;
        nv.z = pref[i].z * mkv; nv.w = pref[i].w * mkv;
        __builtin_nontemporal_store(nv, oslab + idx);
    }
#pragma unroll
    for (int i = 8; i < 16; i++) {
        int idx = t + 256 * i;
        float4 v = pslab[idx];
        float mkv = mks[ns * 32 + (idx >> 7)];
        nfloat4 nv;
        nv.x = v.x * mkv; nv.y = v.y * mkv; nv.z = v.z * mkv; nv.w = v.w * mkv;
        __builtin_nontemporal_store(nv, oslab + idx);
    }
}

extern "C" void kernel_launch(void* const* d_in, const int* in_sizes, int n_in,
                              void* d_out, int out_size, void* d_ws, size_t ws_size,
                              hipStream_t stream) {
    const float* rgb   = (const float*)d_in[0];
    const float* nir   = (const float*)d_in[1];
    const float* tir   = (const float*)d_in[2];
    const float* rgb_g = (const float*)d_in[3];
    const float* nir_g = (const float*)d_in[4];
    const float* tir_g = (const float*)d_in[5];
    const float* attn_qw = (const float*)d_in[6];
    const float* attn_qb = (const float*)d_in[7];
    const float* attn_kw = (const float*)d_in[8];
    const float* attn_kb = (const float*)d_in[9];
    const float* mlp_w1 = (const float*)d_in[10];
    const float* mlp_b1 = (const float*)d_in[11];
    const float* ln_g = (const float*)d_in[12];
    const float* ln_b = (const float*)d_in[13];
    const float* mlp_w2 = (const float*)d_in[14];
    const float* mlp_b2 = (const float*)d_in[15];
    const float* mlp_w3 = (const float*)d_in[16];
    const float* mlp_b3 = (const float*)d_in[17];
    float* out = (float*)d_out;

    float* ws = (float*)d_ws;
    // layout (floats):
    float* part     = ws;                // 8*294912 = 2359296
    float* kpart    = ws + 2359296;      // 2359296
    float* qkb_part = ws + 4718592;      // 9*8*64 = 4608 -> pad 5120
    float* h1part   = ws + 4723712;      // 12*3*64*256 = 589824
    float* lgt      = ws + 5313536;      // 3*64*3*256 = 147456
    float* gn       = ws + 5460992;      // 3*64*512 = 98304
    float* wmix     = ws + 5559296;      // 3*64*4 = 768 -> pad 1024
    float* scrap    = ws + 5560320;      // 512 (warm-chunk sums, write-only)
    // total 5560832 floats = 22.2 MB

    k_proj_mlp<<<1023, 256, 0, stream>>>(rgb_g, nir_g, tir_g, attn_qw, mlp_w1,
                                         rgb, nir, tir, part, h1part, gn, scrap);
    k_kproj<<<dim3(13, 9, 8), 256, 0, stream>>>(attn_kw, part, attn_qb, attn_kb,
                                                h1part, mlp_b1, ln_g, ln_b,
                                                mlp_w2, mlp_b2, mlp_w3, mlp_b3,
                                                rgb, nir, tir,
                                                kpart, qkb_part, wmix, scrap);
    k_logits<<<dim3(B, 3, 8), 256, 0, stream>>>(rgb, nir, tir, kpart, qkb_part, gn, lgt);
    k_finscale<<<dim3(B, 3, 8), 256, 0, stream>>>(lgt, wmix, rgb, nir, tir, out);
}

// Round 16
// 93.621 us; speedup vs baseline: 1.0620x; 1.0620x over previous
//
#include <hip/hip_runtime.h>
#include <math.h>

#define B 64
#define N 256
#define C 512

typedef float nfloat4 __attribute__((ext_vector_type(4)));

// guide modality for module m = 3*mi + j
__device__ __forceinline__ int guide_of(int m) {
    int mi = m / 3, j = m % 3;
    return (j == 0) ? mi : (j == 1 ? ((mi == 0) ? 1 : 0) : ((mi == 2) ? 1 : 2));
}

template<int NW>
__device__ __forceinline__ float breduce_sum(float v, volatile float* red, int t) {
    int w = t >> 6, l = t & 63;
#pragma unroll
    for (int mm = 1; mm < 64; mm <<= 1) v += __shfl_xor(v, mm);
    __syncthreads();
    if (l == 0) red[w] = v;
    __syncthreads();
    float s = red[0];
#pragma unroll
    for (int i = 1; i < NW; i++) s += red[i];
    return s;
}

__device__ __forceinline__ float dot4(float4 a, float4 b) {
    return a.x * b.x + a.y * b.y + a.z * b.z + a.w * b.w;
}

// Fused: qproj partials (blocks 0..575) + mlp fc1 tiles (576..719) + gn (720..722)
__global__ __launch_bounds__(256) void k_proj_mlp(const float* g0, const float* g1, const float* g2,
                                                  const float* qw, const float* w1,
                                                  float* part, float* h1part, float* gn) {
    int bid = blockIdx.x;
    int t = threadIdx.x;
    __shared__ float gt[64 * 132];  // padded stride 132: bank (4b+e)%32, conflict-free
    if (bid < 576) {
        int cx = bid & 7, m = (bid >> 3) % 9, ks = bid / 72;
        int e0 = ks * 64;
        int gi = guide_of(m);
        const float* g = (gi == 0) ? g0 : (gi == 1 ? g1 : g2);
        for (int idx = t; idx < 1024; idx += 256) {
            int r = idx >> 4, c4 = idx & 15;
            ((float4*)&gt[r * 132])[c4] = ((const float4*)(g + (size_t)r * C + e0))[c4];
        }
        __syncthreads();
        int c0 = cx * 64 + 4 * (t & 15);
        int b0 = 4 * (t >> 4);
        float4 acc[4];
#pragma unroll
        for (int j = 0; j < 4; j++) acc[j] = make_float4(0.f, 0.f, 0.f, 0.f);
        const float* W = qw + (size_t)m * C * C + (size_t)e0 * C + c0;
#pragma unroll 4
        for (int e = 0; e < 64; e++) {
            float4 wv = *(const float4*)(W + (size_t)e * C);
#pragma unroll
            for (int j = 0; j < 4; j++) {
                float gv = gt[(b0 + j) * 132 + e];
                acc[j].x += gv * wv.x; acc[j].y += gv * wv.y;
                acc[j].z += gv * wv.z; acc[j].w += gv * wv.w;
            }
        }
#pragma unroll
        for (int j = 0; j < 4; j++)
            *(float4*)(part + (size_t)ks * 294912 + ((size_t)m * B + b0 + j) * C + c0) = acc[j];
    } else if (bid < 720) {
        int r = bid - 576;  // 0..143 : (cx=4, mi=3, ks=12)
        int cx = r & 3, mi = (r >> 2) % 3, ks = r / 12;
        int e0 = ks * 128;
        const float* g = (e0 < 512) ? g0 : (e0 < 1024 ? g1 : g2);
        int eo = e0 & 511;
        for (int idx = t; idx < 2048; idx += 256) {
            int rr = idx >> 5, c4 = idx & 31;
            ((float4*)&gt[rr * 132])[c4] = ((const float4*)(g + (size_t)rr * C + eo))[c4];
        }
        __syncthreads();
        int c0 = cx * 64 + 4 * (t & 15);
        int b0 = 4 * (t >> 4);
        float4 acc[4];
#pragma unroll
        for (int j = 0; j < 4; j++) acc[j] = make_float4(0.f, 0.f, 0.f, 0.f);
        const float* W = w1 + ((size_t)mi * 1536 + e0) * 256 + c0;
#pragma unroll 4
        for (int e = 0; e < 128; e++) {
            float4 wv = *(const float4*)(W + (size_t)e * 256);
#pragma unroll
            for (int j = 0; j < 4; j++) {
                float gv = gt[(b0 + j) * 132 + e];
                acc[j].x += gv * wv.x; acc[j].y += gv * wv.y;
                acc[j].z += gv * wv.z; acc[j].w += gv * wv.w;
            }
        }
#pragma unroll
        for (int j = 0; j < 4; j++)
            *(float4*)(h1part + (((size_t)ks * 3 + mi) * B + b0 + j) * 256 + c0) = acc[j];
    } else {
        int gm = bid - 720;  // 0..2
        const float* g = (gm == 0) ? g0 : (gm == 1 ? g1 : g2);
        int wv = t >> 6, l = t & 63;
        for (int r = wv; r < 64; r += 4) {
            const float4* gv = (const float4*)(g + (size_t)r * C);
            float4 a = gv[l], b2 = gv[64 + l];
            float n2 = dot4(a, a) + dot4(b2, b2);
#pragma unroll
            for (int mm = 1; mm < 64; mm <<= 1) n2 += __shfl_xor(n2, mm);
            float inv = 1.0f / fmaxf(sqrtf(n2), 1e-8f);
            float4* o = (float4*)(gn + ((size_t)gm * B + r) * C);
            a.x *= inv; a.y *= inv; a.z *= inv; a.w *= inv;
            b2.x *= inv; b2.y *= inv; b2.z *= inv; b2.w *= inv;
            o[l] = a; o[64 + l] = b2;
        }
    }
}

// kpart[ds][m][b][c] = sum_{d in slice ds} kw[m,c,d]*q[m,b,d] (cx<8, 4x4 tiling)
// cx>=8: 192 blocks compute the adaptive-weight MLP once per (mi,b) -> wmix.
__global__ __launch_bounds__(256) void k_kproj(const float* kw, const float* part,
                                               const float* qb, const float* kb,
                                               const float* h1part,
                                               const float* b1, const float* lng, const float* lnb,
                                               const float* w2, const float* b2,
                                               const float* w3, const float* b3,
                                               float* kpart, float* qkb_part, float* wmix) {
    int cx = blockIdx.x, m = blockIdx.y, ds = blockIdx.z;
    int t = threadIdx.x;
    if (cx >= 8) {
        int widx = (cx - 8) * 72 + m * 8 + ds;  // 0..215
        if (widx >= 192) return;
        int mi = widx >> 6;    // 0..2
        int b = widx & 63;
        __shared__ float h1[256];
        __shared__ float h2p[4][64];
        __shared__ float h2[64];
        __shared__ float redm[4];
        float a1 = b1[mi * 256 + t];
#pragma unroll
        for (int ks = 0; ks < 12; ks++) a1 += h1part[(((size_t)ks * 3 + mi) * B + b) * 256 + t];
        float total = breduce_sum<4>(a1, redm, t);
        float mean = total * (1.0f / 256.0f);
        float dv = a1 - mean;
        float vtot = breduce_sum<4>(dv * dv, redm, t);
        float var = vtot * (1.0f / 256.0f);
        float x = dv / sqrtf(var + 1e-5f) * lng[mi * 256 + t] + lnb[mi * 256 + t];
        x = 0.5f * x * (1.0f + erff(x * 0.70710678118654752f));
        h1[t] = x;
        __syncthreads();
        {
            int col = t & 63, sl = t >> 6;
            float a2 = 0.f;
            const float* W2 = w2 + (size_t)mi * 256 * 64 + col;
#pragma unroll 8
            for (int e = sl * 64; e < sl * 64 + 64; e++) a2 += h1[e] * W2[(size_t)e * 64];
            h2p[sl][col] = a2;
        }
        __syncthreads();
        if (t < 64) {
            float a2 = b2[mi * 64 + t];
#pragma unroll
            for (int s2 = 0; s2 < 4; s2++) a2 += h2p[s2][t];
            a2 = 0.5f * a2 * (1.0f + erff(a2 * 0.70710678118654752f));
            h2[t] = a2;
        }
        __syncthreads();
        if (t == 0) {
            float l3[3];
            for (int j = 0; j < 3; j++) {
                float a3 = b3[mi * 3 + j];
                for (int e = 0; e < 64; e++) a3 += h2[e] * w3[((size_t)mi * 64 + e) * 3 + j];
                l3[j] = a3;
            }
            float mx = fmaxf(l3[0], fmaxf(l3[1], l3[2]));
            float e0 = expf(l3[0] - mx), e1 = expf(l3[1] - mx), e2 = expf(l3[2] - mx);
            float inv = 1.0f / (e0 + e1 + e2);
            wmix[((size_t)mi * B + b) * 4 + 0] = e0 * inv;
            wmix[((size_t)mi * B + b) * 4 + 1] = e1 * inv;
            wmix[((size_t)mi * B + b) * 4 + 2] = e2 * inv;
        }
        return;
    }
    int c0b = cx * 64, d0 = ds * 64;
    __shared__ float kt[64][65];  // [c][d] padded: bank (c+d)%32
    __shared__ float qt[64][65];  // [b][d] padded
    for (int idx = t; idx < 1024; idx += 256) {
        int r = idx >> 4, c4 = idx & 15;
        float4 kv4 = *(const float4*)(kw + ((size_t)m * C + c0b + r) * C + d0 + c4 * 4);
        kt[r][c4 * 4 + 0] = kv4.x; kt[r][c4 * 4 + 1] = kv4.y;
        kt[r][c4 * 4 + 2] = kv4.z; kt[r][c4 * 4 + 3] = kv4.w;
        float4 s = *(const float4*)(qb + (size_t)m * C + d0 + c4 * 4);
        const float* pp = part + ((size_t)m * B + r) * C + d0 + c4 * 4;
#pragma unroll
        for (int ks = 0; ks < 8; ks++) {
            float4 v = *(const float4*)(pp + (size_t)ks * 294912);
            s.x += v.x; s.y += v.y; s.z += v.z; s.w += v.w;
        }
        qt[r][c4 * 4 + 0] = s.x; qt[r][c4 * 4 + 1] = s.y;
        qt[r][c4 * 4 + 2] = s.z; qt[r][c4 * 4 + 3] = s.w;
    }
    __syncthreads();
    int c0 = 4 * (t & 15);
    int b0 = 4 * (t >> 4);
    float4 acc[4];
#pragma unroll
    for (int j = 0; j < 4; j++) acc[j] = make_float4(0.f, 0.f, 0.f, 0.f);
#pragma unroll 4
    for (int d = 0; d < 64; d++) {
        float k0 = kt[c0 + 0][d], k1 = kt[c0 + 1][d], k2 = kt[c0 + 2][d], k3 = kt[c0 + 3][d];
#pragma unroll
        for (int j = 0; j < 4; j++) {
            float qv = qt[b0 + j][d];
            acc[j].x += qv * k0; acc[j].y += qv * k1;
            acc[j].z += qv * k2; acc[j].w += qv * k3;
        }
    }
#pragma unroll
    for (int j = 0; j < 4; j++)
        *(float4*)(kpart + (size_t)ds * 294912 + ((size_t)m * B + b0 + j) * C + c0b + c0) = acc[j];
    if (cx == 0 && t < 64) {
        float s = 0.f;
        const float* kbp = kb + (size_t)m * C + d0;
        for (int d = 0; d < 64; d++) s += qt[t][d] * kbp[d];
        qkb_part[((size_t)m * 8 + ds) * B + t] = s;
    }
}

// logits: grid (B, 3, 8) x 256; 32 tokens/block; 8 lanes/token; gn precomputed.
// First 8 patch float4s are issued into registers BEFORE the q6 staging so the
// HBM stream overlaps the (L2-bound) kpart-reduce staging phase.
__global__ __launch_bounds__(256) void k_logits(const float* p0, const float* p1, const float* p2,
                                                const float* kpart, const float* qkb_part,
                                                const float* gn, float* lgt) {
    int b = blockIdx.x, mi = blockIdx.y, ns = blockIdx.z;
    int t = threadIdx.x, w = t >> 6, l = t & 63;
    const float* p = (mi == 0) ? p0 : (mi == 1 ? p1 : p2);
    int s = l & 7, tl = l >> 3;
    int n = ns * 32 + w * 8 + tl;
    const float4* pbase = (const float4*)(p + (size_t)b * N * C);
    const float4* prow = pbase + (size_t)n * 128;
    float4 pf[8];
#pragma unroll
    for (int i = 0; i < 8; i++) pf[i] = prow[s + 8 * i];
    __shared__ float q6[6][512];
    __shared__ float qkb_s[3];
    for (int idx = t; idx < 768; idx += 256) {
        int row = idx >> 7, c4 = idx & 127;
        float4 v;
        if (row < 3) {
            int m = 3 * mi + row;
            const float4* kp = (const float4*)kpart + ((size_t)m * B + b) * 128 + c4;
            v = kp[0];
#pragma unroll
            for (int ds = 1; ds < 8; ds++) {
                float4 u = kp[(size_t)ds * 73728];
                v.x += u.x; v.y += u.y; v.z += u.z; v.w += u.w;
            }
        } else {
            int gi = guide_of(3 * mi + row - 3);
            v = ((const float4*)(gn + ((size_t)gi * B + b) * C))[c4];
        }
        ((float4*)q6[row])[c4] = v;
    }
    if (t < 3) {
        int m = 3 * mi + t;
        float sq = 0.f;
#pragma unroll
        for (int ds = 0; ds < 8; ds++) sq += qkb_part[((size_t)m * 8 + ds) * B + b];
        qkb_s[t] = sq;
    }
    __syncthreads();
    const float SCALE = 0.044194173824159216f;  // 512^-0.5
    float* L = lgt + (size_t)(mi * B + b) * 3 * N;
    const float4* Q0 = (const float4*)q6[0];
    const float4* Q1 = (const float4*)q6[1];
    const float4* Q2 = (const float4*)q6[2];
    const float4* G0 = (const float4*)q6[3];
    const float4* G1 = (const float4*)q6[4];
    const float4* G2 = (const float4*)q6[5];
    {
        float pp = 0.f, dj0 = 0.f, dj1 = 0.f, dj2 = 0.f, cj0 = 0.f, cj1 = 0.f, cj2 = 0.f;
#pragma unroll
        for (int i = 0; i < 16; i++) {
            int o = s + 8 * i;
            float4 pv = (i < 8) ? pf[i] : prow[o];
            pp  += dot4(pv, pv);
            dj0 += dot4(pv, Q0[o]);
            dj1 += dot4(pv, Q1[o]);
            dj2 += dot4(pv, Q2[o]);
            cj0 += dot4(pv, G0[o]);
            cj1 += dot4(pv, G1[o]);
            cj2 += dot4(pv, G2[o]);
        }
#pragma unroll
        for (int mm = 1; mm < 8; mm <<= 1) {
            pp  += __shfl_xor(pp, mm);
            dj0 += __shfl_xor(dj0, mm);
            dj1 += __shfl_xor(dj1, mm);
            dj2 += __shfl_xor(dj2, mm);
            cj0 += __shfl_xor(cj0, mm);
            cj1 += __shfl_xor(cj1, mm);
            cj2 += __shfl_xor(cj2, mm);
        }
        if (s == 0) {
            float rn = fmaxf(sqrtf(pp), 1e-8f);
            float ic = 1.0f / (rn * 0.3f);
            L[0 * N + n] = (dj0 + qkb_s[0]) * SCALE + cj0 * ic;
            L[1 * N + n] = (dj1 + qkb_s[1]) * SCALE + cj1 * ic;
            L[2 * N + n] = (dj2 + qkb_s[2]) * SCALE + cj2 * ic;
        }
    }
}

// finscale: grid (B, 3, 8) x 256, forward order. Prologue is now ONLY the
// score phase (MLP moved to k_kproj spare blocks -> wmix). Logit loads issue
// first, then the 8-float4 slab prefetch (cached loads drain under the score
// phase via in-order vmcnt). Score-phase reductions batched 3-wide: 24 -> 8
// syncthreads; per-value butterfly+combine order identical to before.
__global__ __launch_bounds__(256) void k_finscale(const float* lgt, const float* wmix,
                                                  const float* p0, const float* p1, const float* p2,
                                                  float* out) {
    int b = blockIdx.x, mi = blockIdx.y, ns = blockIdx.z, t = threadIdx.x;
    int w = t >> 6, l = t & 63;
    const float* L = lgt + (size_t)(mi * B + b) * 3 * N;
    float wj0 = wmix[((size_t)mi * B + b) * 4 + 0];
    float wj1 = wmix[((size_t)mi * B + b) * 4 + 1];
    float wj2 = wmix[((size_t)mi * B + b) * 4 + 2];
    float v0 = L[0 * N + t], v1 = L[1 * N + t], v2 = L[2 * N + t];
    // slab prefetch issued after the logit loads: compiler waits at vmcnt(8)
    const float* p = (mi == 0) ? p0 : (mi == 1 ? p1 : p2);
    const float4* pslab = (const float4*)(p + (size_t)b * N * C + (size_t)ns * 32 * C);
    float4 pref[8];
#pragma unroll
    for (int i = 0; i < 8; i++) pref[i] = pslab[t + 256 * i];
    __shared__ float red3[3][4];
    __shared__ float sc[256];
    __shared__ float mks[256];
    __shared__ float thr_s;
    // round 1: batched max
    float m0 = v0, m1 = v1, m2 = v2;
#pragma unroll
    for (int mm = 1; mm < 64; mm <<= 1) {
        m0 = fmaxf(m0, __shfl_xor(m0, mm));
        m1 = fmaxf(m1, __shfl_xor(m1, mm));
        m2 = fmaxf(m2, __shfl_xor(m2, mm));
    }
    __syncthreads();
    if (l == 0) { red3[0][w] = m0; red3[1][w] = m1; red3[2][w] = m2; }
    __syncthreads();
    float mx0 = red3[0][0], mx1 = red3[1][0], mx2 = red3[2][0];
#pragma unroll
    for (int i = 1; i < 4; i++) {
        mx0 = fmaxf(mx0, red3[0][i]); mx1 = fmaxf(mx1, red3[1][i]); mx2 = fmaxf(mx2, red3[2][i]);
    }
    float e0 = expf(v0 - mx0), e1 = expf(v1 - mx1), e2 = expf(v2 - mx2);
    // round 2: batched sum of e
    float s0 = e0, s1 = e1, s2 = e2;
#pragma unroll
    for (int mm = 1; mm < 64; mm <<= 1) {
        s0 += __shfl_xor(s0, mm); s1 += __shfl_xor(s1, mm); s2 += __shfl_xor(s2, mm);
    }
    __syncthreads();
    if (l == 0) { red3[0][w] = s0; red3[1][w] = s1; red3[2][w] = s2; }
    __syncthreads();
    float t0 = red3[0][0], t1 = red3[1][0], t2 = red3[2][0];
#pragma unroll
    for (int i = 1; i < 4; i++) { t0 += red3[0][i]; t1 += red3[1][i]; t2 += red3[2][i]; }
    float pr0 = e0 / t0, pr1 = e1 / t1, pr2 = e2 / t2;
    // round 3: batched sum of pr
    float u0 = pr0, u1 = pr1, u2 = pr2;
#pragma unroll
    for (int mm = 1; mm < 64; mm <<= 1) {
        u0 += __shfl_xor(u0, mm); u1 += __shfl_xor(u1, mm); u2 += __shfl_xor(u2, mm);
    }
    __syncthreads();
    if (l == 0) { red3[0][w] = u0; red3[1][w] = u1; red3[2][w] = u2; }
    __syncthreads();
    float tt0 = red3[0][0], tt1 = red3[1][0], tt2 = red3[2][0];
#pragma unroll
    for (int i = 1; i < 4; i++) { tt0 += red3[0][i]; tt1 += red3[1][i]; tt2 += red3[2][i]; }
    float dv0 = pr0 - tt0 * (1.0f / 256.0f);
    float dv1 = pr1 - tt1 * (1.0f / 256.0f);
    float dv2 = pr2 - tt2 * (1.0f / 256.0f);
    // round 4: batched sum of dv*dv
    float q0 = dv0 * dv0, q1 = dv1 * dv1, q2 = dv2 * dv2;
#pragma unroll
    for (int mm = 1; mm < 64; mm <<= 1) {
        q0 += __shfl_xor(q0, mm); q1 += __shfl_xor(q1, mm); q2 += __shfl_xor(q2, mm);
    }
    __syncthreads();
    if (l == 0) { red3[0][w] = q0; red3[1][w] = q1; red3[2][w] = q2; }
    __syncthreads();
    float vt0 = red3[0][0], vt1 = red3[1][0], vt2 = red3[2][0];
#pragma unroll
    for (int i = 1; i < 4; i++) { vt0 += red3[0][i]; vt1 += red3[1][i]; vt2 += red3[2][i]; }
    float sd0 = sqrtf(vt0 * (1.0f / 255.0f)) + 1e-5f;
    float sd1 = sqrtf(vt1 * (1.0f / 255.0f)) + 1e-5f;
    float sd2 = sqrtf(vt2 * (1.0f / 255.0f)) + 1e-5f;
    float sg0 = 1.0f / (1.0f + expf(-(dv0 / sd0)));
    float sg1 = 1.0f / (1.0f + expf(-(dv1 / sd1)));
    float sg2 = 1.0f / (1.0f + expf(-(dv2 / sd2)));
    float score = wj0 * sg0;
    score += wj1 * sg1;
    score += wj2 * sg2;
    sc[t] = score;
    __syncthreads();
    {
        int cl = 0, ce = 0;
        for (int m2i = 0; m2i < N; m2i++) {
            float v2i = sc[m2i];
            cl += (v2i < score) ? 1 : 0;
            ce += (v2i == score) ? 1 : 0;
        }
        if (cl <= 102 && 102 < cl + ce) thr_s = score;
    }
    __syncthreads();
    float thr = thr_s;
    float mk = 1.0f / (1.0f + expf(-(score - thr) * (1.0f / 0.3f)));
    mks[t] = mk;
    if ((t >> 5) == ns)
        out[(size_t)3 * B * N * C + ((size_t)mi * B + b) * N + t] = mk;
    __syncthreads();
    // --- store phase: prefetched 8, then stream the last 8 ---
    nfloat4* oslab = (nfloat4*)(out + (size_t)mi * B * N * C + (size_t)b * N * C
                                + (size_t)ns * 32 * C);
#pragma unroll
    for (int i = 0; i < 8; i++) {
        int idx = t + 256 * i;
        float mkv = mks[ns * 32 + (idx >> 7)];
        nfloat4 nv;
        nv.x = pref[i].x * mkv; nv.y = pref[i].y * mkv;
        nv.z = pref[i].z * mkv; nv.w = pref[i].w * mkv;
        __builtin_nontemporal_store(nv, oslab + idx);
    }
#pragma unroll
    for (int i = 8; i < 16; i++) {
        int idx = t + 256 * i;
        float4 v = pslab[idx];
        float mkv = mks[ns * 32 + (idx >> 7)];
        nfloat4 nv;
        nv.x = v.x * mkv; nv.y = v.y * mkv; nv.z = v.z * mkv; nv.w = v.w * mkv;
        __builtin_nontemporal_store(nv, oslab + idx);
    }
}

extern "C" void kernel_launch(void* const* d_in, const int* in_sizes, int n_in,
                              void* d_out, int out_size, void* d_ws, size_t ws_size,
                              hipStream_t stream) {
    const float* rgb   = (const float*)d_in[0];
    const float* nir   = (const float*)d_in[1];
    const float* tir   = (const float*)d_in[2];
    const float* rgb_g = (const float*)d_in[3];
    const float* nir_g = (const float*)d_in[4];
    const float* tir_g = (const float*)d_in[5];
    const float* attn_qw = (const float*)d_in[6];
    const float* attn_qb = (const float*)d_in[7];
    const float* attn_kw = (const float*)d_in[8];
    const float* attn_kb = (const float*)d_in[9];
    const float* mlp_w1 = (const float*)d_in[10];
    const float* mlp_b1 = (const float*)d_in[11];
    const float* ln_g = (const float*)d_in[12];
    const float* ln_b = (const float*)d_in[13];
    const float* mlp_w2 = (const float*)d_in[14];
    const float* mlp_b2 = (const float*)d_in[15];
    const float* mlp_w3 = (const float*)d_in[16];
    const float* mlp_b3 = (const float*)d_in[17];
    float* out = (float*)d_out;

    float* ws = (float*)d_ws;
    // layout (floats):
    float* part     = ws;                // 8*294912 = 2359296
    float* kpart    = ws + 2359296;      // 2359296
    float* qkb_part = ws + 4718592;      // 9*8*64 = 4608 -> pad 5120
    float* h1part   = ws + 4723712;      // 12*3*64*256 = 589824
    float* lgt      = ws + 5313536;      // 3*64*3*256 = 147456
    float* gn       = ws + 5460992;      // 3*64*512 = 98304
    float* wmix     = ws + 5559296;      // 3*64*4 = 768
    // total 5560064 floats = 22.2 MB

    k_proj_mlp<<<723, 256, 0, stream>>>(rgb_g, nir_g, tir_g, attn_qw, mlp_w1,
                                        part, h1part, gn);
    k_kproj<<<dim3(11, 9, 8), 256, 0, stream>>>(attn_kw, part, attn_qb, attn_kb,
                                                h1part, mlp_b1, ln_g, ln_b,
                                                mlp_w2, mlp_b2, mlp_w3, mlp_b3,
                                                kpart, qkb_part, wmix);
    k_logits<<<dim3(B, 3, 8), 256, 0, stream>>>(rgb, nir, tir, kpart, qkb_part, gn, lgt);
    k_finscale<<<dim3(B, 3, 8), 256, 0, stream>>>(lgt, wmix, rgb, nir, tir, out);
}